// Round 1
// baseline (221.849 us; speedup 1.0000x reference)
//
#include <hip/hip_runtime.h>
#include <cmath>

#define NB     8
#define NVERT  14062
#define NV3    42186      // NVERT*3
#define BATCH  256
#define KP     63         // P rows used (bones 1..7, 9 each)
#define KE     55         // E rows
#define KPAD   120        // padded K (2 zero rows)
#define KT     8          // k-tile
#define NSTEP  15         // KPAD/KT
#define VT     32         // vertices per block in GEMM
#define BT     16         // batches per block in epilogue

// ---------------- Kernel 1: per-batch setup ----------------
__device__ inline void mat4mul(const float* A, const float* B, float* C) {
#pragma unroll
  for (int i = 0; i < 4; i++)
#pragma unroll
    for (int j = 0; j < 4; j++) {
      float s = 0.f;
#pragma unroll
      for (int k = 0; k < 4; k++) s = fmaf(A[i*4+k], B[k*4+j], s);
      C[i*4+j] = s;
    }
}

__global__ void setup_kernel(const float* __restrict__ theta,  // [256][8][3]
                             const float* __restrict__ bsw,    // [256][55]
                             const float* __restrict__ L2P,    // [8][4][4]
                             float* __restrict__ coef_t,       // [120][256]
                             float* __restrict__ mats)         // [256][8][12]
{
  int b = blockIdx.x * blockDim.x + threadIdx.x;
  if (b >= BATCH) return;

  float R[NB][9];
#pragma unroll
  for (int n = 0; n < NB; n++) {
    float rx = theta[(b*NB+n)*3+0];
    float ry = theta[(b*NB+n)*3+1];
    float rz = theta[(b*NB+n)*3+2];
    float ang = sqrtf(rx*rx + ry*ry + rz*rz + 1e-12f);
    float kx = rx/ang, ky = ry/ang, kz = rz/ang;
    float s = sinf(ang), c = cosf(ang);
    float K[9] = {0.f,-kz,ky,  kz,0.f,-kx,  -ky,kx,0.f};
    float K2[9];
#pragma unroll
    for (int i = 0; i < 3; i++)
#pragma unroll
      for (int j = 0; j < 3; j++) {
        float v = 0.f;
#pragma unroll
        for (int k = 0; k < 3; k++) v = fmaf(K[i*3+k], K[k*3+j], v);
        K2[i*3+j] = v;
      }
#pragma unroll
    for (int e = 0; e < 9; e++) {
      int i = e/3, j = e%3;
      R[n][e] = (i==j ? 1.f : 0.f) + s*K[e] + (1.f-c)*K2[e];
    }
  }

  // coef rows 0..62: theta_zero for bones 1..7 (bone 0 is exactly zero)
#pragma unroll
  for (int n = 1; n < NB; n++)
#pragma unroll
    for (int e = 0; e < 9; e++) {
      int i = e/3, j = e%3;
      coef_t[((n-1)*9+e)*BATCH + b] = R[n][e] - (i==j ? 1.f : 0.f);
    }
  // rows 63..117: bsw
  for (int s2 = 0; s2 < KE; s2++)
    coef_t[(KP+s2)*BATCH + b] = bsw[b*KE + s2];
  coef_t[118*BATCH + b] = 0.f;
  coef_t[119*BATCH + b] = 0.f;

  // FK chain + rest chain + rigid inverse + skin matrices
  float prevPose[16], prevRest[16];
#pragma unroll 1
  for (int n = 0; n < NB; n++) {
    float loc[16] = {R[n][0],R[n][1],R[n][2],0.f,
                     R[n][3],R[n][4],R[n][5],0.f,
                     R[n][6],R[n][7],R[n][8],0.f,
                     0.f,0.f,0.f,1.f};
    float A[16], pose[16], rest[16];
    mat4mul(&L2P[n*16], loc, A);
    if (n == 0) {
#pragma unroll
      for (int q = 0; q < 16; q++) { pose[q] = A[q]; rest[q] = L2P[q]; }
    } else {
      mat4mul(prevPose, A, pose);
      mat4mul(prevRest, &L2P[n*16], rest);
    }
    // rigid inverse of rest: [R^T, -R^T t]
    float w2l[16];
#pragma unroll
    for (int i = 0; i < 3; i++) {
#pragma unroll
      for (int j = 0; j < 3; j++) w2l[i*4+j] = rest[j*4+i];
      w2l[i*4+3] = -(rest[0*4+i]*rest[0*4+3] + rest[1*4+i]*rest[1*4+3] + rest[2*4+i]*rest[2*4+3]);
    }
    w2l[12]=0.f; w2l[13]=0.f; w2l[14]=0.f; w2l[15]=1.f;
    float skin[16];
    mat4mul(pose, w2l, skin);
#pragma unroll
    for (int i = 0; i < 3; i++)
#pragma unroll
      for (int j = 0; j < 4; j++)
        mats[(size_t)b*96 + n*12 + i*4 + j] = skin[i*4+j];
#pragma unroll
    for (int q = 0; q < 16; q++) { prevPose[q] = pose[q]; prevRest[q] = rest[q]; }
  }
}

// ---------------- Kernel 2: GEMM  T_theta_partial = coef @ D ----------------
// D rows: c in [0,63) -> P + (9+c)*NV3 ;  c in [63,118) -> E + (c-63)*NV3
__global__ __launch_bounds__(256) void gemm_kernel(
    const float* __restrict__ P, const float* __restrict__ E,
    const float* __restrict__ coef_t, float* __restrict__ Tth)
{
  __shared__ float dlds[KT][VT*3];    // 8 x 96
  __shared__ float clds[KT][BATCH];   // 8 x 256

  int tid = threadIdx.x;
  int vt  = tid & 7;    // owns 4 consecutive vertices: vt*4 .. vt*4+3 (in tile)
  int bg  = tid >> 3;   // owns batches bg*8 .. bg*8+7
  int vbase = blockIdx.x * VT;
  size_t vbase3 = (size_t)vbase * 3;
  bool full = (vbase + VT) <= NVERT;

  float acc[8][12];
#pragma unroll
  for (int j = 0; j < 8; j++)
#pragma unroll
    for (int x = 0; x < 12; x++) acc[j][x] = 0.f;

  for (int step = 0; step < NSTEP; step++) {
    int c0 = step * KT;
    __syncthreads();
    // stage D tile: 8 rows x 96 floats (192 float4)
    if (tid < 192) {
      int r = tid / 24, q = tid % 24;
      int c = c0 + r;
      const float* src = (c < KP) ? (P + (size_t)(9 + c) * NV3)
                                  : (E + (size_t)((c < 118 ? c : 117) - KP) * NV3);
      if (full) {
        float4 v = *reinterpret_cast<const float4*>(src + vbase3 + q*4);
        *reinterpret_cast<float4*>(&dlds[r][q*4]) = v;
      } else {
#pragma unroll
        for (int u = 0; u < 4; u++) {
          size_t idx = vbase3 + q*4 + u;
          if (idx >= NV3) idx = NV3 - 1;
          dlds[r][q*4+u] = src[idx];
        }
      }
    }
    // stage coef tile: 8 rows x 256 floats (512 float4, 2/thread)
#pragma unroll
    for (int rep = 0; rep < 2; rep++) {
      int f = tid + rep * 256;
      int r = f >> 6, pos = f & 63;
      float4 v = *reinterpret_cast<const float4*>(coef_t + (size_t)(c0+r)*BATCH + pos*4);
      *reinterpret_cast<float4*>(&clds[r][pos*4]) = v;
    }
    __syncthreads();

#pragma unroll
    for (int k = 0; k < KT; k++) {
      float4 ca = *reinterpret_cast<const float4*>(&clds[k][bg*8]);
      float4 cb = *reinterpret_cast<const float4*>(&clds[k][bg*8+4]);
      float4 d0 = *reinterpret_cast<const float4*>(&dlds[k][vt*12+0]);
      float4 d1 = *reinterpret_cast<const float4*>(&dlds[k][vt*12+4]);
      float4 d2 = *reinterpret_cast<const float4*>(&dlds[k][vt*12+8]);
      float cf[8] = {ca.x,ca.y,ca.z,ca.w, cb.x,cb.y,cb.z,cb.w};
      float dv[12] = {d0.x,d0.y,d0.z,d0.w, d1.x,d1.y,d1.z,d1.w, d2.x,d2.y,d2.z,d2.w};
#pragma unroll
      for (int j = 0; j < 8; j++)
#pragma unroll
        for (int x = 0; x < 12; x++)
          acc[j][x] = fmaf(cf[j], dv[x], acc[j][x]);
    }
  }

  // store partial T_theta (without T, without larynx term)
#pragma unroll
  for (int j = 0; j < 8; j++) {
    int b = bg*8 + j;
    if (full) {
      float4* dst = reinterpret_cast<float4*>(Tth + (size_t)b*NV3 + vbase3 + vt*12);
      float4 o0 = {acc[j][0],acc[j][1],acc[j][2],acc[j][3]};
      float4 o1 = {acc[j][4],acc[j][5],acc[j][6],acc[j][7]};
      float4 o2 = {acc[j][8],acc[j][9],acc[j][10],acc[j][11]};
      dst[0] = o0; dst[1] = o1; dst[2] = o2;
    } else {
#pragma unroll
      for (int x = 0; x < 12; x++) {
        size_t idx = vbase3 + vt*12 + x;
        if (idx < NV3) Tth[(size_t)b*NV3 + idx] = acc[j][x];
      }
    }
  }
}

// ---------------- Kernel 3: epilogue (bilinear + T + LBS) ----------------
__global__ __launch_bounds__(256) void epilogue_kernel(
    const float* __restrict__ Tth, const float* __restrict__ mats, // [256][96]
    const float* __restrict__ Wm,   // [8][NVERT]
    const float* __restrict__ T,    // [NVERT][3]
    const float* __restrict__ ts,   // [NVERT][3]
    const float* __restrict__ uvgrid, // [NVERT][2]
    const float* __restrict__ Limg,   // [256][256]
    const float* __restrict__ tau, const float* __restrict__ alpha,
    float* __restrict__ out)
{
  __shared__ float mlds[BT][96];
  __shared__ float tau_s[BT], alpha_s[BT];
  int tid = threadIdx.x;
  int b0 = blockIdx.y * BT;

  for (int f = tid; f < BT*24; f += 256) {
    int bb = f / 24, q = f % 24;
    float4 v = *reinterpret_cast<const float4*>(mats + (size_t)(b0+bb)*96 + q*4);
    *reinterpret_cast<float4*>(&mlds[bb][q*4]) = v;
  }
  if (tid < BT) { tau_s[tid] = tau[b0+tid]; alpha_s[tid] = alpha[b0+tid]; }
  __syncthreads();

  int v = blockIdx.x * 256 + tid;
  if (v >= NVERT) return;

  float W8[NB];
#pragma unroll
  for (int n = 0; n < NB; n++) W8[n] = Wm[(size_t)n*NVERT + v];
  float T0 = T[v*3+0], T1 = T[v*3+1], T2 = T[v*3+2];
  float s0 = ts[v*3+0], s1 = ts[v*3+1], s2 = ts[v*3+2];
  float uv0 = uvgrid[v*2+0], uv1 = uvgrid[v*2+1];

  // x-coordinate of bilinear sample is batch-independent
  float gx = uv0*2.f - 1.f;
  float xc = fminf(fmaxf((gx+1.f)*0.5f*255.f, 0.f), 255.f);
  float x0 = floorf(xc);
  int x0i = (int)x0;
  int x1i = min(x0i+1, 255);
  float wx = xc - x0;
  float gy_base = uv1*2.f - 1.f;

#pragma unroll 1
  for (int bi = 0; bi < BT; bi++) {
    int b = b0 + bi;
    // bilinear sample
    float gy = gy_base + 2.f*tau_s[bi];
    float yc = fminf(fmaxf((gy+1.f)*0.5f*255.f, 0.f), 255.f);
    float y0 = floorf(yc);
    int y0i = (int)y0;
    int y1i = min(y0i+1, 255);
    float wy = yc - y0;
    float v00 = Limg[y0i*256 + x0i], v01 = Limg[y0i*256 + x1i];
    float v10 = Limg[y1i*256 + x0i], v11 = Limg[y1i*256 + x1i];
    float dist = (v00*(1.f-wx) + v01*wx)*(1.f-wy) + (v10*(1.f-wx) + v11*wx)*wy;
    float da = dist * alpha_s[bi];

    size_t tbase = (size_t)b*NV3 + (size_t)v*3;
    float xv0 = Tth[tbase+0] + T0 + da*s0;
    float xv1 = Tth[tbase+1] + T1 + da*s1;
    float xv2 = Tth[tbase+2] + T2 + da*s2;

    float o[3];
#pragma unroll
    for (int i = 0; i < 3; i++) {
      float r0=0.f, r1=0.f, r2=0.f, r3=0.f;
#pragma unroll
      for (int n = 0; n < NB; n++) {
        float4 m = *reinterpret_cast<const float4*>(&mlds[bi][n*12 + i*4]);
        float w = W8[n];
        r0 = fmaf(w, m.x, r0); r1 = fmaf(w, m.y, r1);
        r2 = fmaf(w, m.z, r2); r3 = fmaf(w, m.w, r3);
      }
      o[i] = fmaf(r0, xv0, fmaf(r1, xv1, fmaf(r2, xv2, r3)));
    }
    out[tbase+0] = o[0];
    out[tbase+1] = o[1];
    out[tbase+2] = o[2];
  }
}

// ---------------- launcher ----------------
extern "C" void kernel_launch(void* const* d_in, const int* in_sizes, int n_in,
                              void* d_out, int out_size, void* d_ws, size_t ws_size,
                              hipStream_t stream)
{
  const float* theta  = (const float*)d_in[0];
  const float* tau    = (const float*)d_in[1];
  const float* alpha  = (const float*)d_in[2];
  const float* bsw    = (const float*)d_in[3];
  const float* Wm     = (const float*)d_in[4];
  const float* T      = (const float*)d_in[5];
  const float* P      = (const float*)d_in[6];
  const float* L      = (const float*)d_in[7];
  const float* ts     = (const float*)d_in[8];
  const float* L2P    = (const float*)d_in[9];
  const float* E      = (const float*)d_in[10];
  const float* uvgrid = (const float*)d_in[11];
  float* out = (float*)d_out;

  float* Tth    = (float*)d_ws;                    // BATCH*NV3 floats (43.2 MB)
  float* coef_t = Tth + (size_t)BATCH * NV3;       // KPAD*BATCH floats
  float* mats   = coef_t + (size_t)KPAD * BATCH;   // BATCH*96 floats

  setup_kernel<<<dim3(4), dim3(64), 0, stream>>>(theta, bsw, L2P, coef_t, mats);
  gemm_kernel<<<dim3((NVERT + VT - 1) / VT), dim3(256), 0, stream>>>(P, E, coef_t, Tth);
  epilogue_kernel<<<dim3((NVERT + 255) / 256, BATCH / BT), dim3(256), 0, stream>>>(
      Tth, mats, Wm, T, ts, uvgrid, L, tau, alpha, out);
}